// Round 9
// baseline (681.338 us; speedup 1.0000x reference)
//
#include <hip/hip_runtime.h>

typedef __attribute__((ext_vector_type(8))) short s8v;
typedef __attribute__((ext_vector_type(4))) short s4v;
typedef __attribute__((ext_vector_type(4))) float f4v;

#if __has_builtin(__builtin_amdgcn_exp2f)
#define EXP2(x) __builtin_amdgcn_exp2f(x)
#else
#define EXP2(x) exp2f(x)
#endif
#if __has_builtin(__builtin_amdgcn_rcpf)
#define RCP(x) __builtin_amdgcn_rcpf(x)
#else
#define RCP(x) (1.0f/(x))
#endif

#define LOG2E 1.4426950408889634f

__device__ __forceinline__ short f2bf(float f) {
    union { float f; unsigned u; } x; x.f = f;
    unsigned r = (x.u + 0x7FFFu + ((x.u >> 16) & 1u)) >> 16;
    return (short)r;
}
__device__ __forceinline__ float bf2f(short s) {
    union { unsigned u; float f; } x; x.u = ((unsigned)(unsigned short)s) << 16;
    return x.f;
}
// LDS-visibility barrier WITHOUT vmcnt drain (keeps prefetch/stores in flight).
__device__ __forceinline__ void lds_barrier() {
    asm volatile("s_waitcnt lgkmcnt(0)\n\ts_barrier" ::: "memory");
}

// ---------------- prep (weights->bf16 B-frag, sigmoid pre-scale) + embed MLP, fused ----------------
__global__ __launch_bounds__(256) void prep_embed_kernel(
        const float* __restrict__ k1f, const float* __restrict__ r1f,
        const float* __restrict__ k1b, const float* __restrict__ r1b,
        const float* __restrict__ k2f, const float* __restrict__ r2f,
        const float* __restrict__ k2b, const float* __restrict__ r2b,
        short* __restrict__ WB1, short* __restrict__ WB2,
        const int* __restrict__ inputA, const float* __restrict__ emb,
        const float* __restrict__ w1, const float* __restrict__ b1,
        const float* __restrict__ w2, const float* __restrict__ b2,
        const float* __restrict__ w3, const float* __restrict__ b3,
        float* __restrict__ xe) {
    if (blockIdx.x < 1024) {
        int idx = blockIdx.x * 256 + threadIdx.x;
        if (idx < 262144) {  // 2*32*8*64*8
            int j = idx & 7, l = (idx >> 3) & 63, c = (idx >> 9) & 7, n = (idx >> 12) & 31, d = (idx >> 17) & 1;
            int coln = n * 16 + (l & 15);
            int k = c * 32 + ((l >> 4) * 8) + j;
            const float* Wk = d ? k1b : k1f;
            const float* Wr = d ? r1b : r1f;
            float v = (c < 4) ? Wk[k * 512 + coln] : Wr[(k - 128) * 512 + coln];
            float sc = ((n >> 3) == 2) ? 1.0f : -LOG2E;  // gate: 0=i,1=f,2=cc,3=o
            WB1[idx] = f2bf(v * sc);
        }
        if (idx < 163840) {  // 2*16*10*64*8
            int d = idx / 81920, r0 = idx % 81920;
            int n = r0 / 5120, r1 = r0 % 5120;
            int c = r1 / 512, li = r1 % 512;
            int l = li >> 3, j = li & 7;
            int coln = n * 16 + (l & 15);
            int k = c * 32 + ((l >> 4) * 8) + j;
            const float* Wk = d ? k2b : k2f;
            const float* Wr = d ? r2b : r2f;
            float v = (k < 256) ? Wk[k * 256 + coln] : Wr[(k - 256) * 256 + coln];
            float sc = ((n >> 2) == 2) ? 1.0f : -LOG2E;
            WB2[idx] = f2bf(v * sc);
        }
        return;
    }
    __shared__ float row[600];
    __shared__ float h1[256];
    __shared__ float h2[128];
    int b = blockIdx.x - 1024, t = threadIdx.x;
    if (t < 200) {
        int idx = inputA[b * 200 + t];
        row[t * 3 + 0] = emb[idx * 3 + 0];
        row[t * 3 + 1] = emb[idx * 3 + 1];
        row[t * 3 + 2] = emb[idx * 3 + 2];
    }
    __syncthreads();
    float a = b1[t];
    for (int k = 0; k < 600; k++) a += row[k] * w1[k * 256 + t];
    h1[t] = fmaxf(a, 0.f);
    __syncthreads();
    if (t < 128) {
        float a2 = b2[t];
        for (int k = 0; k < 256; k++) a2 += h1[k] * w2[k * 128 + t];
        h2[t] = fmaxf(a2, 0.f);
    }
    __syncthreads();
    if (t < 64) {
        float a3 = b3[t];
        for (int k = 0; k < 128; k++) a3 += h2[k] * w3[k * 64 + t];
        xe[b * 64 + t] = fmaxf(a3, 0.f);
    }
}

// ---- lstm1 step macro: 8-deep prefetch (PA/PB refilled for step SIDX+8) ----
#define L1_STEP(SRC, DST, PA, PB, SIDX) do { \
    s8v ah[4]; \
    _Pragma("unroll") \
    for (int cc = 0; cc < 4; cc++) ah[cc] = *(const s8v*)&SRC[(cc * 64 + lane) * 8]; \
    if (w >= 4 && (SIDX) > 0) { \
        int tp = t0 + (SIDX) - 1; if (dir) tp = 511 - tp; \
        s8v hv = (w == 4) ? ah[0] : (w == 5) ? ah[1] : (w == 6) ? ah[2] : ah[3]; \
        *(s8v*)(ybase + (size_t)tp * 4096) = hv; \
    } \
    f4v acc[4]; \
    _Pragma("unroll") \
    for (int r = 0; r < 4; r++) { \
        acc[0][r] = bf2f(PA[r]); acc[1][r] = bf2f(PA[4 + r]); \
        acc[2][r] = bf2f(PB[r]); acc[3][r] = bf2f(PB[4 + r]); \
    } \
    { const short* np = xgp + (size_t)((SIDX) + 8) * 8192; \
      PA = *(const s8v*)np; PB = *(const s8v*)(np + 512); } \
    _Pragma("unroll") \
    for (int cc = 0; cc < 4; cc++) { \
        _Pragma("unroll") \
        for (int ti = 0; ti < 4; ti++) \
            acc[ti] = __builtin_amdgcn_mfma_f32_16x16x32_bf16(ah[cc], wf[ti][cc], acc[ti], 0, 0, 0); \
    } \
    _Pragma("unroll") \
    for (int r = 0; r < 4; r++) { \
        float iv = RCP(1.0f + EXP2(acc[0][r])); \
        float fv = RCP(1.0f + EXP2(acc[1][r])); \
        float ov = RCP(1.0f + EXP2(acc[3][r])); \
        float ccv = fmaxf(acc[2][r], 0.f); \
        cst[r] = fv * cst[r] + iv * ccv; \
        hl[r] = ov * fmaxf(cst[r], 0.f); \
    } \
    _Pragma("unroll") \
    for (int r = 0; r < 4; r++) DST[hidx + ((q * 4 + r) << 3)] = f2bf(hl[r]); \
    lds_barrier(); \
} while (0)

// ---- lstm2 step macro (waves 0-3 compute; all waves hit the barrier) ----
#define L2_STEP(SRC, DST, PA, PB, SIDX) do { \
    if (w < 4) { \
        s8v ah[2]; \
        _Pragma("unroll") \
        for (int cc = 0; cc < 2; cc++) ah[cc] = *(const s8v*)&SRC[(cc * 64 + lane) * 8]; \
        f4v acc[4]; \
        _Pragma("unroll") \
        for (int r = 0; r < 4; r++) { \
            acc[0][r] = bf2f(PA[r]); acc[1][r] = bf2f(PA[4 + r]); \
            acc[2][r] = bf2f(PB[r]); acc[3][r] = bf2f(PB[4 + r]); \
        } \
        { const short* np = ygp + (size_t)((SIDX) + 8) * 4096; \
          PA = *(const s8v*)np; PB = *(const s8v*)(np + 512); } \
        _Pragma("unroll") \
        for (int cc = 0; cc < 2; cc++) { \
            _Pragma("unroll") \
            for (int ti = 0; ti < 4; ti++) \
                acc[ti] = __builtin_amdgcn_mfma_f32_16x16x32_bf16(ah[cc], wf[ti][cc], acc[ti], 0, 0, 0); \
        } \
        _Pragma("unroll") \
        for (int r = 0; r < 4; r++) { \
            float iv = RCP(1.0f + EXP2(acc[0][r])); \
            float fv = RCP(1.0f + EXP2(acc[1][r])); \
            float ov = RCP(1.0f + EXP2(acc[3][r])); \
            float ccv = fmaxf(acc[2][r], 0.f); \
            cst[r] = fv * cst[r] + iv * ccv; \
            hl[r] = ov * fmaxf(cst[r], 0.f); \
        } \
        _Pragma("unroll") \
        for (int r = 0; r < 4; r++) DST[hidx + ((q * 4 + r) << 3)] = f2bf(hl[r]); \
    } \
    lds_barrier(); \
} while (0)

// ---------------- megastep: one pipeline super-step per launch ----------------
// 84KB static LDS -> 1 block/CU (exclusion verified R8). Blocks 0..63 recurrence,
// 64..255 looping gemm workers. launch k: lstm1(k-1) | lstm2(k-3) | gemm1(k) | gemm2(k-2).
__global__ __launch_bounds__(512, 2) void megastep(
        const float* __restrict__ x, const short* __restrict__ WB1, const short* __restrict__ WB2,
        const float* __restrict__ bb1f, const float* __restrict__ bb1b,
        const float* __restrict__ bb2f, const float* __restrict__ bb2b,
        short* __restrict__ yfr, short* __restrict__ xgA, short* __restrict__ xgB,
        short* __restrict__ ygA, short* __restrict__ ygB,
        float* __restrict__ c1st, short* __restrict__ h1st,
        float* __restrict__ c2st, short* __restrict__ h2st,
        float* __restrict__ h2o, int k, int TC, int NC) {
    __shared__ short hA[2048];      // 4KB
    __shared__ short hB[2048];      // 4KB
    __shared__ short stg[38912];    // 76KB (gemm1 staging uses first 32KB; rest pads occupancy)
    const int tid = threadIdx.x, lane = tid & 63, w = tid >> 6;
    const int bid = blockIdx.x;
    const int tgn = TC >> 3;

    if (bid < 32) {
        // ================= LSTM1 role: chunk cl = k-1 =================
        const int cl = k - 1;
        if (cl < 0 || cl >= NC) return;
        const int t0 = cl * TC;
        const int first = (cl == 0);
        const int btile = bid & 15, dir = bid >> 4;
        const int col = lane & 15, q = lane >> 4, u = (w << 4) + col;
        const int sb = dir * 16 + btile;

        s8v wf[4][4];  // h-part chunks 4..7
#pragma unroll
        for (int ti = 0; ti < 4; ti++)
#pragma unroll
            for (int c = 0; c < 4; c++)
                wf[ti][c] = *(const s8v*)(WB1 + ((((dir * 32 + (w + 8 * ti)) * 8) + 4 + c) * 64 + lane) * 8);

        float cst[4], hl[4];
        if (first) {
#pragma unroll
            for (int r = 0; r < 4; r++) cst[r] = 0.f;
            for (int i = tid; i < 2048; i += 512) hA[i] = 0;
        } else {
            f4v cv = *(const f4v*)(c1st + ((size_t)sb * 8 + w) * 256 + lane * 4);
#pragma unroll
            for (int r = 0; r < 4; r++) cst[r] = cv[r];
            for (int i = tid; i < 2048; i += 512) hA[i] = h1st[sb * 2048 + i];
        }
        __syncthreads();

        const short* xgp = ((cl & 1) ? xgB : xgA) + (size_t)sb * TC * 8192 + w * 1024 + lane * 8;
        short* ybase = yfr + ((size_t)btile * 4096 + dir * 4 + ((w >= 4) ? (w - 4) : 0)) * 512 + lane * 8;
        // 8-deep prefetch prologue (named regs only)
        s8v E0a = *(const s8v*)(xgp + 0 * 8192), E0b = *(const s8v*)(xgp + 0 * 8192 + 512);
        s8v O0a = *(const s8v*)(xgp + 1 * 8192), O0b = *(const s8v*)(xgp + 1 * 8192 + 512);
        s8v E1a = *(const s8v*)(xgp + 2 * 8192), E1b = *(const s8v*)(xgp + 2 * 8192 + 512);
        s8v O1a = *(const s8v*)(xgp + 3 * 8192), O1b = *(const s8v*)(xgp + 3 * 8192 + 512);
        s8v E2a = *(const s8v*)(xgp + 4 * 8192), E2b = *(const s8v*)(xgp + 4 * 8192 + 512);
        s8v O2a = *(const s8v*)(xgp + 5 * 8192), O2b = *(const s8v*)(xgp + 5 * 8192 + 512);
        s8v E3a = *(const s8v*)(xgp + 6 * 8192), E3b = *(const s8v*)(xgp + 6 * 8192 + 512);
        s8v O3a = *(const s8v*)(xgp + 7 * 8192), O3b = *(const s8v*)(xgp + 7 * 8192 + 512);

        const int hidx = (w >> 1) * 512 + ((u >> 3) & 3) * 128 + (u & 7);

        for (int s = 0; s < TC; s += 8) {
            L1_STEP(hA, hB, E0a, E0b, s + 0);
            L1_STEP(hB, hA, O0a, O0b, s + 1);
            L1_STEP(hA, hB, E1a, E1b, s + 2);
            L1_STEP(hB, hA, O1a, O1b, s + 3);
            L1_STEP(hA, hB, E2a, E2b, s + 4);
            L1_STEP(hB, hA, O2a, O2b, s + 5);
            L1_STEP(hA, hB, E3a, E3b, s + 6);
            L1_STEP(hB, hA, O3a, O3b, s + 7);
        }
        if (w >= 4) {  // final h(TC-1) (loop ends with hA holding it)
            int tp = t0 + TC - 1;
            if (dir) tp = 511 - tp;
            s8v hv = *(const s8v*)&hA[((w - 4) * 64 + lane) * 8];
            *(s8v*)(ybase + (size_t)tp * 4096) = hv;
        }
        f4v cv;
#pragma unroll
        for (int r = 0; r < 4; r++) cv[r] = cst[r];
        *(f4v*)(c1st + ((size_t)sb * 8 + w) * 256 + lane * 4) = cv;
        for (int i = tid; i < 2048; i += 512) h1st[sb * 2048 + i] = hA[i];
        return;
    }

    if (bid < 64) {
        // ================= LSTM2 role: chunk c2 = k-3 =================
        const int c2 = k - 3;
        if (c2 < 0 || c2 >= NC) return;
        const int first = (c2 == 0), last = (c2 == NC - 1);
        const int btile = (bid - 32) & 15, dir = (bid - 32) >> 4;
        const int b0 = btile << 4;
        const int w4 = w & 3;
        const int col = lane & 15, q = lane >> 4, u = (w4 << 4) + col;
        const int sb = dir * 16 + btile;

        s8v wf[4][2];  // h-part chunks 8,9
#pragma unroll
        for (int ti = 0; ti < 4; ti++)
#pragma unroll
            for (int c = 0; c < 2; c++)
                wf[ti][c] = *(const s8v*)(WB2 + ((((dir * 16 + (w4 + 4 * ti)) * 10) + 8 + c) * 64 + lane) * 8);

        float cst[4], hl[4] = {0.f, 0.f, 0.f, 0.f};
        if (first) {
#pragma unroll
            for (int r = 0; r < 4; r++) cst[r] = 0.f;
            for (int i = tid; i < 1024; i += 512) hA[i] = 0;
        } else {
            f4v cv = *(const f4v*)(c2st + ((size_t)sb * 4 + w4) * 256 + lane * 4);
#pragma unroll
            for (int r = 0; r < 4; r++) cst[r] = cv[r];
            for (int i = tid; i < 1024; i += 512) hA[i] = h2st[sb * 1024 + i];
        }
        __syncthreads();

        const short* ygp = ((c2 & 1) ? ygB : ygA) + (size_t)sb * TC * 4096 + w4 * 1024 + lane * 8;
        s8v E0a, E0b, O0a, O0b, E1a, E1b, O1a, O1b, E2a, E2b, O2a, O2b, E3a, E3b, O3a, O3b;
        if (w < 4) {
            E0a = *(const s8v*)(ygp + 0 * 4096); E0b = *(const s8v*)(ygp + 0 * 4096 + 512);
            O0a = *(const s8v*)(ygp + 1 * 4096); O0b = *(const s8v*)(ygp + 1 * 4096 + 512);
            E1a = *(const s8v*)(ygp + 2 * 4096); E1b = *(const s8v*)(ygp + 2 * 4096 + 512);
            O1a = *(const s8v*)(ygp + 3 * 4096); O1b = *(const s8v*)(ygp + 3 * 4096 + 512);
            E2a = *(const s8v*)(ygp + 4 * 4096); E2b = *(const s8v*)(ygp + 4 * 4096 + 512);
            O2a = *(const s8v*)(ygp + 5 * 4096); O2b = *(const s8v*)(ygp + 5 * 4096 + 512);
            E3a = *(const s8v*)(ygp + 6 * 4096); E3b = *(const s8v*)(ygp + 6 * 4096 + 512);
            O3a = *(const s8v*)(ygp + 7 * 4096); O3b = *(const s8v*)(ygp + 7 * 4096 + 512);
        }
        const int hidx = (w4 >> 1) * 512 + ((u >> 3) & 3) * 128 + (u & 7);

        for (int s = 0; s < TC; s += 8) {
            L2_STEP(hA, hB, E0a, E0b, s + 0);
            L2_STEP(hB, hA, O0a, O0b, s + 1);
            L2_STEP(hA, hB, E1a, E1b, s + 2);
            L2_STEP(hB, hA, O1a, O1b, s + 3);
            L2_STEP(hA, hB, E2a, E2b, s + 4);
            L2_STEP(hB, hA, O2a, O2b, s + 5);
            L2_STEP(hA, hB, E3a, E3b, s + 6);
            L2_STEP(hB, hA, O3a, O3b, s + 7);
        }
        if (w < 4) {
            f4v cv;
#pragma unroll
            for (int r = 0; r < 4; r++) cv[r] = cst[r];
            *(f4v*)(c2st + ((size_t)sb * 4 + w4) * 256 + lane * 4) = cv;
        }
        __syncthreads();
        for (int i = tid; i < 1024; i += 512) h2st[sb * 1024 + i] = hA[i];
        if (last && w < 4) {
#pragma unroll
            for (int r = 0; r < 4; r++)
                h2o[((dir * 256) + b0 + q * 4 + r) * 64 + u] = hl[r];
        }
        return;
    }

    // ================= GEMM workers: 192 blocks looping over tasks =================
    {
        const int wid = bid - 64;
        const int n1 = (k < NC) ? 4 * TC : 0;
        const int n2 = (k >= 2 && (k - 2) < NC) ? 4 * TC : 0;
        for (int tsk = wid; tsk < n1 + n2; tsk += 192) {
            if (tsk < n1) {
                // ---- gemm1 task: xg(k) = x @ Wk + b ----
                const int cg = k;
                const int t0 = cg * TC;
                const int g = tsk;
                const int btile = g & 15;
                const int rest = g >> 4;
                const int tg = rest % tgn;
                const int dir = rest / tgn;
                const int b0 = btile << 4;
                short* xg_w = (cg & 1) ? xgB : xgA;
                __syncthreads();  // protect stg reuse across tasks
                {   // stage A frags (coalesced 512B segments + XOR swizzle)
                    int tglob = t0 + tg * 8 + w;
                    if (dir) tglob = 511 - tglob;
                    const int half = lane >> 5;
                    const int f0 = (lane & 31) * 4;
                    const int cx = f0 >> 5, qq = (f0 >> 3) & 3, j0 = f0 & 7;
#pragma unroll
                    for (int rr = 0; rr < 8; rr++) {
                        const int m = rr * 2 + half;
                        const float* xp = x + ((size_t)(b0 + m) * 512 + tglob) * 128 + f0;
                        f4v v4 = *(const f4v*)xp;
                        const int slot = (qq << 4) | ((m ^ qq ^ (cx << 1)) & 15);
                        s4v pk;
#pragma unroll
                        for (int j = 0; j < 4; j++) pk[j] = f2bf(v4[j]);
                        *(s4v*)&stg[(((w * 4 + cx) * 64 + slot) * 8) + j0] = pk;
                    }
                }
                s8v wf[4][4];
#pragma unroll
                for (int ti = 0; ti < 4; ti++)
#pragma unroll
                    for (int c = 0; c < 4; c++)
                        wf[ti][c] = *(const s8v*)(WB1 + ((((dir * 32 + (w + 8 * ti)) * 8) + c) * 64 + lane) * 8);
                const float* bb = dir ? bb1b : bb1f;
                float bias[4];
#pragma unroll
                for (int ti = 0; ti < 4; ti++) {
                    const int tile = w + 8 * ti;
                    float sc = ((tile >> 3) == 2) ? 1.0f : -LOG2E;
                    bias[ti] = sc * bb[tile * 16 + (lane & 15)];
                }
                __syncthreads();
                const size_t sb = dir * 16 + btile;
#pragma unroll 2
                for (int sl = 0; sl < 8; sl++) {
                    s8v a[4];
#pragma unroll
                    for (int c = 0; c < 4; c++) {
                        const int slot = lane ^ (lane >> 4) ^ (c << 1);
                        a[c] = *(const s8v*)&stg[((sl * 4 + c) * 64 + slot) * 8];
                    }
                    f4v acc[4];
#pragma unroll
                    for (int ti = 0; ti < 4; ti++) { f4v z = {0.f, 0.f, 0.f, 0.f}; acc[ti] = z; }
#pragma unroll
                    for (int c = 0; c < 4; c++)
#pragma unroll
                        for (int ti = 0; ti < 4; ti++)
                            acc[ti] = __builtin_amdgcn_mfma_f32_16x16x32_bf16(a[c], wf[ti][c], acc[ti], 0, 0, 0);
                    short* outp = xg_w + ((sb * TC + (size_t)(tg * 8 + sl)) * 8 + w) * 1024 + lane * 8;
#pragma unroll
                    for (int p = 0; p < 2; p++) {
                        s8v v;
#pragma unroll
                        for (int j = 0; j < 4; j++) {
                            v[j]     = f2bf(acc[2 * p][j]     + bias[2 * p]);
                            v[4 + j] = f2bf(acc[2 * p + 1][j] + bias[2 * p + 1]);
                        }
                        *(s8v*)(outp + p * 512) = v;
                    }
                }
            } else {
                // ---- gemm2 task: yg(k-2) = y @ Wk2 + b ----
                const int cg = k - 2;
                const int t0 = cg * TC;
                const int g = tsk - n1;
                const int btile = g & 15;
                const int rest = g >> 4;
                const int tg = rest % tgn;
                const int dir = rest / tgn;
                short* yg_w = (cg & 1) ? ygB : ygA;
                const int w4 = w & 3, sh = (w >> 2) * 4;
                s8v wf[4][8];
#pragma unroll
                for (int ti = 0; ti < 4; ti++)
#pragma unroll
                    for (int c = 0; c < 8; c++)
                        wf[ti][c] = *(const s8v*)(WB2 + ((((dir * 16 + (w4 + 4 * ti)) * 10) + c) * 64 + lane) * 8);
                const float* bb = dir ? bb2b : bb2f;
                float bias[4];
#pragma unroll
                for (int ti = 0; ti < 4; ti++) {
                    const int tile = w4 + 4 * ti;
                    float sc = ((tile >> 2) == 2) ? 1.0f : -LOG2E;
                    bias[ti] = sc * bb[tile * 16 + (lane & 15)];
                }
                const size_t sb = dir * 16 + btile;
#pragma unroll
                for (int si = 0; si < 4; si++) {
                    const int sl = sh + si;
                    int tglob = t0 + tg * 8 + sl;
                    if (dir) tglob = 511 - tglob;
                    s8v a[8];
#pragma unroll
                    for (int c = 0; c < 8; c++)
                        a[c] = *(const s8v*)(yfr + (((size_t)(btile * 512 + tglob) * 8) + c) * 512 + lane * 8);
                    f4v acc[4];
#pragma unroll
                    for (int ti = 0; ti < 4; ti++) { f4v z = {0.f, 0.f, 0.f, 0.f}; acc[ti] = z; }
#pragma unroll
                    for (int c = 0; c < 8; c++)
#pragma unroll
                        for (int ti = 0; ti < 4; ti++)
                            acc[ti] = __builtin_amdgcn_mfma_f32_16x16x32_bf16(a[c], wf[ti][c], acc[ti], 0, 0, 0);
                    short* outp = yg_w + ((sb * TC + (size_t)(tg * 8 + sl)) * 4 + w4) * 1024 + lane * 8;
#pragma unroll
                    for (int p = 0; p < 2; p++) {
                        s8v v;
#pragma unroll
                        for (int j = 0; j < 4; j++) {
                            v[j]     = f2bf(acc[2 * p][j]     + bias[2 * p]);
                            v[4 + j] = f2bf(acc[2 * p + 1][j] + bias[2 * p + 1]);
                        }
                        *(s8v*)(outp + p * 512) = v;
                    }
                }
            }
        }
    }
}

// ---------------- final heads (fp32) ----------------
__global__ void heads_kernel(const float* __restrict__ xe, const float* __restrict__ h2o,
                             const float* __restrict__ wz1, const float* __restrict__ bz1,
                             const float* __restrict__ wz2, const float* __restrict__ bz2,
                             const float* __restrict__ wt1, const float* __restrict__ bt1,
                             const float* __restrict__ wt2, const float* __restrict__ bt2,
                             float* __restrict__ out) {
    int b = threadIdx.x;  // 256 threads, 1 block
    float cz0 = bz1[0], cz1 = bz1[1], ct0 = bt1[0], ct1 = bt1[1];
    for (int k = 0; k < 192; k++) {
        float v = (k < 64) ? xe[b * 64 + k]
                : (k < 128) ? h2o[b * 64 + (k - 64)]
                            : h2o[(256 + b) * 64 + (k - 128)];
        cz0 += v * wz1[k * 2 + 0];
        cz1 += v * wz1[k * 2 + 1];
        ct0 += v * wt1[k * 2 + 0];
        ct1 += v * wt1[k * 2 + 1];
    }
    cz0 = fmaxf(cz0, 0.f); cz1 = fmaxf(cz1, 0.f);
    ct0 = fmaxf(ct0, 0.f); ct1 = fmaxf(ct1, 0.f);
    out[b] = cz0 * wz2[0] + cz1 * wz2[1] + bz2[0];
    out[256 + b] = ct0 * wt2[0] + ct1 * wt2[1] + bt2[0];
}

extern "C" void kernel_launch(void* const* d_in, const int* in_sizes, int n_in,
                              void* d_out, int out_size, void* d_ws, size_t ws_size,
                              hipStream_t stream) {
    const int*   inputA = (const int*)d_in[0];
    const float* inputB = (const float*)d_in[1];
    const float* emb = (const float*)d_in[2];
    const float* w1  = (const float*)d_in[3];
    const float* b1  = (const float*)d_in[4];
    const float* w2  = (const float*)d_in[5];
    const float* b2  = (const float*)d_in[6];
    const float* w3  = (const float*)d_in[7];
    const float* b3  = (const float*)d_in[8];
    const float* k1f = (const float*)d_in[9];
    const float* r1f = (const float*)d_in[10];
    const float* bb1f= (const float*)d_in[11];
    const float* k1b = (const float*)d_in[12];
    const float* r1b = (const float*)d_in[13];
    const float* bb1b= (const float*)d_in[14];
    const float* k2f = (const float*)d_in[15];
    const float* r2f = (const float*)d_in[16];
    const float* bb2f= (const float*)d_in[17];
    const float* k2b = (const float*)d_in[18];
    const float* r2b = (const float*)d_in[19];
    const float* bb2b= (const float*)d_in[20];
    const float* wz1 = (const float*)d_in[21];
    const float* bz1 = (const float*)d_in[22];
    const float* wz2 = (const float*)d_in[23];
    const float* bz2 = (const float*)d_in[24];
    const float* wt1 = (const float*)d_in[25];
    const float* bt1 = (const float*)d_in[26];
    const float* wt2 = (const float*)d_in[27];
    const float* bt2 = (const float*)d_in[28];

    char* ws = (char*)d_ws;
    short* WB1  = (short*)(ws);                  // 512 KB
    short* WB2  = (short*)(ws + 524288);         // 320 KB
    float* xe   = (float*)(ws + 851968);         // 64 KB
    float* h2o  = (float*)(ws + 917504);         // 128 KB
    float* c1st = (float*)(ws + 1048576);        // 256 KB
    short* h1st = (short*)(ws + 1310720);        // 128 KB
    float* c2st = (float*)(ws + 1441792);        // 128 KB
    short* h2st = (short*)(ws + 1572864);        // 64 KB
    short* yfr  = (short*)(ws + 2097152);        // 67.1 MB
    float* out  = (float*)d_out;

    // chunk size: need fixed + 2*xg + 2*yg + prefetch over-read slack
    int TC = 32;
    if (69206016ull + 2ull * 64 * 524288 + 2ull * 64 * 262144 + 262144 <= ws_size) TC = 64;
    const int NC = 512 / TC;
    short* xgA = (short*)(ws + 69206016);
    short* xgB = xgA + (size_t)TC * 262144;
    short* ygA = xgB + (size_t)TC * 262144;
    short* ygB = ygA + (size_t)TC * 131072;
    const int grid = 256;  // 64 recurrence + 192 looping gemm workers

    prep_embed_kernel<<<1280, 256, 0, stream>>>(k1f, r1f, k1b, r1b, k2f, r2f, k2b, r2b,
                                                WB1, WB2, inputA, emb, w1, b1, w2, b2, w3, b3, xe);
    for (int k = 0; k < NC + 3; k++) {
        megastep<<<grid, 512, 0, stream>>>(inputB, WB1, WB2, bb1f, bb1b, bb2f, bb2b,
                                           yfr, xgA, xgB, ygA, ygB,
                                           c1st, h1st, c2st, h2st, h2o, k, TC, NC);
    }
    heads_kernel<<<1, 256, 0, stream>>>(xe, h2o, wz1, bz1, wz2, bz2, wt1, bt1, wt2, bt2, out);
}